// Round 1
// baseline (2148.043 us; speedup 1.0000x reference)
//
#include <hip/hip_runtime.h>
#include <hip/hip_bf16.h>
#include <cstdint>
#include <cstddef>

#define IN_DIM 4096
#define OUT_DIM 32768
#define BATCH 4096
#define EPS 1e-8f

typedef __attribute__((ext_vector_type(4))) float f32x4;
typedef __attribute__((ext_vector_type(8))) short bf16x8;

__device__ __forceinline__ unsigned short f2bf(float f) {
    union { float f; unsigned int u; } v;
    v.f = f;
    unsigned int u = v.u;
    // round-to-nearest-even to bf16
    unsigned int r = (u + 0x7FFFu + ((u >> 16) & 1u)) >> 16;
    return (unsigned short)r;
}

__device__ __forceinline__ void load_lds16(const void* g, void* l) {
    __builtin_amdgcn_global_load_lds(
        (const __attribute__((address_space(1))) void*)g,
        (__attribute__((address_space(3))) void*)l,
        16, 0, 0);
}

// ---------------------------------------------------------------------------
// Kernel 1: x (BATCH x IN_DIM fp32) -> bf16, plus per-row inverse norms.
// One block per row, 256 threads, float4 loads (coalesced 16B/lane).
// ---------------------------------------------------------------------------
__global__ void xprep(const float* __restrict__ x,
                      unsigned short* __restrict__ xb,
                      float* __restrict__ xinv) {
    const int row = blockIdx.x;
    const int tid = threadIdx.x;
    const float4* x4 = (const float4*)(x + (size_t)row * IN_DIM);
    ushort4* xb4 = (ushort4*)(xb + (size_t)row * IN_DIM);
    float ss = 0.f;
#pragma unroll
    for (int it = 0; it < IN_DIM / 4 / 256; ++it) {
        int i = it * 256 + tid;
        float4 v = x4[i];
        ss += v.x * v.x + v.y * v.y + v.z * v.z + v.w * v.w;
        ushort4 o;
        o.x = f2bf(v.x); o.y = f2bf(v.y); o.z = f2bf(v.z); o.w = f2bf(v.w);
        xb4[i] = o;
    }
#pragma unroll
    for (int off = 32; off > 0; off >>= 1) ss += __shfl_down(ss, off);
    __shared__ float red[4];
    if ((tid & 63) == 0) red[tid >> 6] = ss;
    __syncthreads();
    if (tid == 0) {
        float s = red[0] + red[1] + red[2] + red[3];
        xinv[row] = 1.f / fmaxf(sqrtf(s), EPS);
    }
}

// ---------------------------------------------------------------------------
// Kernel 2: w (IN_DIM x OUT_DIM fp32, row-major) -> bf16 TRANSPOSED (OUT_DIM x
// IN_DIM), plus column sum-of-squares via LDS + global atomics.
// 64x64 tiles, 256 threads. LDS pad 66 -> conflict-free transposed read.
// ---------------------------------------------------------------------------
__global__ void wprep(const float* __restrict__ w,
                      unsigned short* __restrict__ wt,
                      float* __restrict__ wn2) {
    __shared__ unsigned short tile[64][66];
    __shared__ float colsum[64];
    const int t = threadIdx.x;
    const int j0 = blockIdx.x * 64;  // OUT_DIM (n)
    const int i0 = blockIdx.y * 64;  // IN_DIM  (k)
    if (t < 64) colsum[t] = 0.f;
    __syncthreads();

    const int jj = t & 63;      // column within tile (fixed per thread)
    const int ibase = t >> 6;   // 0..3
    float ss = 0.f;
#pragma unroll
    for (int it = 0; it < 16; ++it) {
        int ii = it * 4 + ibase;
        float v = w[(size_t)(i0 + ii) * OUT_DIM + j0 + jj];
        ss += v * v;
        tile[ii][jj] = f2bf(v);
    }
    atomicAdd(&colsum[jj], ss);
    __syncthreads();
    if (t < 64) atomicAdd(&wn2[j0 + t], colsum[t]);

    // transposed write: lane-contiguous along i (IN_DIM) -> coalesced
    const int ii2 = t & 63;
    const int jbase = t >> 6;
#pragma unroll
    for (int it = 0; it < 16; ++it) {
        int jj2 = it * 4 + jbase;
        wt[(size_t)(j0 + jj2) * IN_DIM + i0 + ii2] = tile[ii2][jj2];
    }
}

// ---------------------------------------------------------------------------
// Kernel 3: wn2 -> inverse norms
// ---------------------------------------------------------------------------
__global__ void wfin(const float* __restrict__ wn2, float* __restrict__ winv) {
    int j = blockIdx.x * 256 + threadIdx.x;
    winv[j] = 1.f / fmaxf(sqrtf(wn2[j]), EPS);
}

// ---------------------------------------------------------------------------
// Kernel 4: GEMM C[m][n] = sum_k A[m][k]*B[n][k], scaled by xinv[m]*winv[n].
// A: BATCH x IN_DIM bf16 (row-major), B: OUT_DIM x IN_DIM bf16 (row-major,
// i.e. w transposed). 128x128 block tile, BK=32, 256 threads = 4 waves,
// each wave 64x64 via 4x4 of 16x16x32 MFMA. global_load_lds width=16.
// ---------------------------------------------------------------------------
#define BM 128
#define BN 128
#define BK 32

__global__ void gemm_kernel(const unsigned short* __restrict__ A,
                            const unsigned short* __restrict__ B,
                            float* __restrict__ C,
                            const float* __restrict__ xinv,
                            const float* __restrict__ winv) {
    __shared__ unsigned short As[BM * BK];  // [m][k], lane-order for load_lds
    __shared__ unsigned short Bs[BN * BK];  // [n][k]

    const int tid = threadIdx.x;
    const int wave = tid >> 6;
    const int lane = tid & 63;
    const int m0 = blockIdx.x * BM;
    const int n0 = blockIdx.y * BN;
    const int wm = (wave & 1) * 64;   // wave's m offset in tile
    const int wn = (wave >> 1) * 64;  // wave's n offset in tile

    f32x4 acc[4][4] = {};

    // staging geometry: 16B chunk per lane; 4 chunks per 32-elem (64B) row
    const int lrow = lane >> 2;           // 0..15
    const int lk = (lane & 3) * 8;        // k element offset of this lane

    const int ml = lane & 15;             // mfma m/n lane index
    const int quad = lane >> 4;           // 0..3

    for (int k0 = 0; k0 < IN_DIM; k0 += BK) {
#pragma unroll
        for (int l = 0; l < 2; ++l) {
            int grow = l * 64 + wave * 16 + lrow;  // 0..127
            const unsigned short* gpa = A + (size_t)(m0 + grow) * IN_DIM + k0 + lk;
            unsigned short* lpa = As + (size_t)(l * 256 + wave * 64) * 8;
            load_lds16(gpa, lpa);
            const unsigned short* gpb = B + (size_t)(n0 + grow) * IN_DIM + k0 + lk;
            unsigned short* lpb = Bs + (size_t)(l * 256 + wave * 64) * 8;
            load_lds16(gpb, lpb);
        }
        __syncthreads();

        bf16x8 af[4], bfr[4];
#pragma unroll
        for (int i = 0; i < 4; ++i) {
            af[i] = *(const bf16x8*)&As[(wm + i * 16 + ml) * BK + quad * 8];
            bfr[i] = *(const bf16x8*)&Bs[(wn + i * 16 + ml) * BK + quad * 8];
        }
#pragma unroll
        for (int i = 0; i < 4; ++i)
#pragma unroll
            for (int j = 0; j < 4; ++j)
                acc[i][j] = __builtin_amdgcn_mfma_f32_16x16x32_bf16(
                    af[i], bfr[j], acc[i][j], 0, 0, 0);
        __syncthreads();
    }

    // epilogue: C/D layout col = lane&15, row = quad*4 + r
    float xs[4][4];
#pragma unroll
    for (int i = 0; i < 4; ++i)
#pragma unroll
        for (int r = 0; r < 4; ++r)
            xs[i][r] = xinv[m0 + wm + i * 16 + quad * 4 + r];

#pragma unroll
    for (int j = 0; j < 4; ++j) {
        int n = n0 + wn + j * 16 + ml;
        float wsc = winv[n];
#pragma unroll
        for (int i = 0; i < 4; ++i) {
            int mbase = m0 + wm + i * 16 + quad * 4;
#pragma unroll
            for (int r = 0; r < 4; ++r) {
                C[(size_t)(mbase + r) * OUT_DIM + n] = acc[i][j][r] * wsc * xs[i][r];
            }
        }
    }
}

// ---------------------------------------------------------------------------
extern "C" void kernel_launch(void* const* d_in, const int* in_sizes, int n_in,
                              void* d_out, int out_size, void* d_ws, size_t ws_size,
                              hipStream_t stream) {
    const float* x = (const float*)d_in[0];
    const float* w = (const float*)d_in[1];
    float* out = (float*)d_out;

    char* ws = (char*)d_ws;
    unsigned short* xb = (unsigned short*)ws;                                // 32 MB
    unsigned short* wt = (unsigned short*)(ws + (size_t)BATCH * IN_DIM * 2); // 256 MB
    char* tail = ws + (size_t)BATCH * IN_DIM * 2 + (size_t)OUT_DIM * IN_DIM * 2;
    float* xinv = (float*)tail;
    float* wn2 = xinv + BATCH;
    float* winv = wn2 + OUT_DIM;

    hipMemsetAsync(wn2, 0, OUT_DIM * sizeof(float), stream);
    xprep<<<BATCH, 256, 0, stream>>>(x, xb, xinv);
    wprep<<<dim3(OUT_DIM / 64, IN_DIM / 64), 256, 0, stream>>>(w, wt, wn2);
    wfin<<<OUT_DIM / 256, 256, 0, stream>>>(wn2, winv);
    gemm_kernel<<<dim3(BATCH / BM, OUT_DIM / BN), 256, 0, stream>>>(xb, wt, out, xinv, winv);
}